// Round 3
// baseline (154.139 us; speedup 1.0000x reference)
//
#include <hip/hip_runtime.h>
#include <math.h>

#define B_ 32
#define S_ 8192
#define D_ 256
#define TS 64               // s-tile width
#define NT (S_ / TS)        // 128 tiles per batch row
#define NBX (NT / 2)        // 64 blocks in x; each block does 2 tiles

// ws layout (floats):
//   wh    [B_*D_]      @ 0
//   ctx   [B_*D_]      @ 8192
//   sc    [B_*S_]      @ 16384
//   ml    [B_*NT*2]    @ 278528
//   opart [B_*NT*D_]   @ 286720
//   mstat [B_*2]       @ 1335296

// K1: wh[b,d] = sum_e W[e,d] * h[b,e]
__global__ __launch_bounds__(256) void k_wh(const float* __restrict__ W,
                                            const float* __restrict__ h,
                                            float* __restrict__ wh) {
  const int b = blockIdx.x;
  const int d = threadIdx.x;
  __shared__ float hs[D_];
  hs[d] = h[b * D_ + d];
  __syncthreads();
  float acc = 0.f;
#pragma unroll 8
  for (int e = 0; e < D_; ++e) acc = fmaf(W[e * D_ + d], hs[e], acc);
  wh[b * D_ + d] = acc;
}

// K2 (fused, pipelined): each block handles 2 s-tiles; tile B's global loads
// are issued into registers before computing tile A so HBM never stalls.
__global__ __launch_bounds__(256, 2) void k_fused(const float* __restrict__ cv,
                                                  const float* __restrict__ wh,
                                                  const int* __restrict__ mask,
                                                  float* __restrict__ sc,
                                                  float* __restrict__ ml,
                                                  float* __restrict__ opart) {
  __shared__ float tile[D_][TS];     // 64 KiB
  __shared__ float whs[D_];
  __shared__ float ps[TS];
  __shared__ float scred[4][TS];
  const int b = blockIdx.y;
  const int t = threadIdx.x;
  const int s = t & 63, dg = t >> 6;
  const int d0 = t >> 4, q0 = (t & 15) * 4;   // staging: rows d0+16*it, cols q0..q0+3
  const float* srcb = cv + (size_t)b * D_ * S_;

  whs[t] = wh[b * D_ + t];

  const int tA = blockIdx.x;         // first tile
  const int tB = blockIdx.x + NBX;   // second tile

  float4 reg[16];
  // load tile A -> regs -> LDS
#pragma unroll
  for (int it = 0; it < 16; ++it)
    reg[it] = *reinterpret_cast<const float4*>(srcb + (size_t)(d0 + 16 * it) * S_ + tA * TS + q0);
#pragma unroll
  for (int it = 0; it < 16; ++it)
    *reinterpret_cast<float4*>(&tile[d0 + 16 * it][q0]) = reg[it];
  __syncthreads();

  // issue tile B loads now; results consumed only after COMPUTE(A)
#pragma unroll
  for (int it = 0; it < 16; ++it)
    reg[it] = *reinterpret_cast<const float4*>(srcb + (size_t)(d0 + 16 * it) * S_ + tB * TS + q0);

#define COMPUTE(T0)                                                              \
  {                                                                              \
    const int s0 = (T0) * TS;                                                    \
    float p0 = 0.f, p1 = 0.f;                                                    \
    _Pragma("unroll")                                                            \
    for (int dd = 0; dd < 64; dd += 2) {                                         \
      p0 = fmaf(tile[dg * 64 + dd][s], whs[dg * 64 + dd], p0);                   \
      p1 = fmaf(tile[dg * 64 + dd + 1][s], whs[dg * 64 + dd + 1], p1);           \
    }                                                                            \
    scred[dg][s] = p0 + p1;                                                      \
    __syncthreads();                                                             \
    if (t < 64) {                                                                \
      float v = scred[0][s] + scred[1][s] + scred[2][s] + scred[3][s];           \
      if (mask[b * S_ + s0 + s] != 0) v = -INFINITY;                             \
      sc[(size_t)b * S_ + s0 + s] = v;                                           \
      float m = v;                                                               \
      for (int off = 32; off > 0; off >>= 1) m = fmaxf(m, __shfl_xor(m, off, 64)); \
      m = fmaxf(m, -1e30f);                                                      \
      const float e = __expf(v - m);                                             \
      ps[s] = e;                                                                 \
      float l = e;                                                               \
      for (int off = 32; off > 0; off >>= 1) l += __shfl_xor(l, off, 64);        \
      if (s == 0) {                                                              \
        ml[((size_t)b * NT + (T0)) * 2] = m;                                     \
        ml[((size_t)b * NT + (T0)) * 2 + 1] = l;                                 \
      }                                                                          \
    }                                                                            \
    __syncthreads();                                                             \
    float acc0 = 0.f;                                                            \
    _Pragma("unroll")                                                            \
    for (int j = 0; j < 64; ++j) {                                               \
      const int ss = (s + j) & 63;                                               \
      acc0 = fmaf(tile[t][ss], ps[ss], acc0);                                    \
    }                                                                            \
    opart[((size_t)b * NT + (T0)) * D_ + t] = acc0;                              \
  }

  COMPUTE(tA);
  __syncthreads();                   // all tile-A LDS reads done
#pragma unroll
  for (int it = 0; it < 16; ++it)
    *reinterpret_cast<float4*>(&tile[d0 + 16 * it][q0]) = reg[it];
  __syncthreads();
  COMPUTE(tB);
#undef COMPUTE
}

// K3: combine per-tile partials -> ctx[b,d] (normalized), plus per-b {M, invL}
__global__ __launch_bounds__(256) void k_combine(const float* __restrict__ ml,
                                                 const float* __restrict__ opart,
                                                 float* __restrict__ ctx,
                                                 float* __restrict__ mstat) {
  const int b = blockIdx.x, t = threadIdx.x;
  __shared__ float em[NT];
  __shared__ float red[4];
  const float m = (t < NT) ? ml[((size_t)b * NT + t) * 2] : -INFINITY;
  const float l = (t < NT) ? ml[((size_t)b * NT + t) * 2 + 1] : 0.f;

  float mm = m;
  for (int off = 32; off > 0; off >>= 1) mm = fmaxf(mm, __shfl_xor(mm, off, 64));
  if ((t & 63) == 0) red[t >> 6] = mm;
  __syncthreads();
  const float M = fmaxf(fmaxf(red[0], red[1]), fmaxf(red[2], red[3]));
  __syncthreads();

  const float e = (t < NT) ? __expf(m - M) : 0.f;
  if (t < NT) em[t] = e;
  float ll = l * e;
  for (int off = 32; off > 0; off >>= 1) ll += __shfl_xor(ll, off, 64);
  if ((t & 63) == 0) red[t >> 6] = ll;
  __syncthreads();
  const float L = red[0] + red[1] + red[2] + red[3];
  const float invL = 1.0f / L;

  float acc = 0.f;
  for (int i = 0; i < NT; ++i)
    acc = fmaf(opart[((size_t)b * NT + i) * D_ + t], em[i], acc);
  ctx[b * D_ + t] = acc * invL;

  if (t == 0) { mstat[b * 2] = M; mstat[b * 2 + 1] = invL; }
}

// K4: out[0:seqlen,B,D] = ctx broadcast; out[..., seqlen,B,S] = exp(sc-M)*invL
__global__ __launch_bounds__(256) void k_bcast(const float4* __restrict__ ctx4,
                                               const float* __restrict__ sc,
                                               const float* __restrict__ mstat,
                                               float4* __restrict__ out4,
                                               long ctxQuads, long total4) {
  const long stride = (long)gridDim.x * blockDim.x;
  for (long idx = (long)blockIdx.x * blockDim.x + threadIdx.x; idx < total4;
       idx += stride) {
    if (idx < ctxQuads) {
      out4[idx] = ctx4[idx & (long)(B_ * D_ / 4 - 1)];
    } else {
      const long q = idx - ctxQuads;
      const long qq = q & (long)(B_ * S_ / 4 - 1);   // pow2
      const int b = (int)(qq >> 11);                  // / (S_/4)
      const int sq = (int)(qq & (S_ / 4 - 1));
      const float M = mstat[b * 2], invL = mstat[b * 2 + 1];
      const float4 v = *reinterpret_cast<const float4*>(sc + (size_t)b * S_ + 4 * sq);
      float4 r;
      r.x = __expf(v.x - M) * invL;
      r.y = __expf(v.y - M) * invL;
      r.z = __expf(v.z - M) * invL;
      r.w = __expf(v.w - M) * invL;
      out4[idx] = r;
    }
  }
}

extern "C" void kernel_launch(void* const* d_in, const int* in_sizes, int n_in,
                              void* d_out, int out_size, void* d_ws, size_t ws_size,
                              hipStream_t stream) {
  // inputs: 0=seqlen(1), 1=hidden(B*D), 2=contextvects(B*D*S), 3=W(D*D),
  //         4=b(D) [softmax-invariant, dropped], 5=padding_mask(B*S)
  const float* hidden = (const float*)d_in[1];
  const float* cv = (const float*)d_in[2];
  const float* W = (const float*)d_in[3];
  const int* mask = (const int*)d_in[5];

  float* ws = (float*)d_ws;
  float* wh = ws;
  float* ctx = ws + 8192;
  float* sc = ws + 16384;
  float* ml = ws + 278528;
  float* opart = ws + 286720;
  float* mstat = ws + 1335296;

  k_wh<<<B_, D_, 0, stream>>>(W, hidden, wh);
  k_fused<<<dim3(NBX, B_), 256, 0, stream>>>(cv, wh, mask, sc, ml, opart);
  k_combine<<<B_, 256, 0, stream>>>(ml, opart, ctx, mstat);

  const long seqlen = (long)out_size / (B_ * D_ + B_ * S_);
  const long ctxQuads = seqlen * B_ * D_ / 4;
  const long total4 = (long)out_size / 4;
  k_bcast<<<2048, 256, 0, stream>>>((const float4*)ctx, sc, mstat,
                                    (float4*)d_out, ctxQuads, total4);
}

// Round 4
// 89.252 us; speedup vs baseline: 1.7270x; 1.7270x over previous
//
#include <hip/hip_runtime.h>
#include <math.h>

#define B_ 32
#define S_ 8192
#define D_ 256
#define TS 32                 // columns per tile
#define TPB 8                 // tiles per block
#define BPB (S_ / (TS * TPB)) // 32 blocks per batch row

// ws layout (floats):
//   wh    [B_*D_]        @ 0
//   ctx   [B_*D_]        @ 8192
//   sc    [B_*S_]        @ 16384
//   ml    [B_*BPB*2]     @ 278528
//   opart [B_*BPB*D_]    @ 280576
//   mstat [B_*2]         @ 542720

// K1: wh[b,d] = sum_e W[e,d] * h[b,e]
__global__ __launch_bounds__(256) void k_wh(const float* __restrict__ W,
                                            const float* __restrict__ h,
                                            float* __restrict__ wh) {
  const int b = blockIdx.x;
  const int d = threadIdx.x;
  __shared__ float hs[D_];
  hs[d] = h[b * D_ + d];
  __syncthreads();
  float acc = 0.f;
#pragma unroll 8
  for (int e = 0; e < D_; ++e) acc = fmaf(W[e * D_ + d], hs[e], acc);
  wh[b * D_ + d] = acc;
}

// K2: register-resident flash pass. Thread t holds rows {t>>3 + 32*it} x
// cols {4*(t&7)..+3} of each 256x32 tile in 8 float4s. Scores reduced via a
// 4KB LDS scratch; context partials accumulated online in registers.
__global__ __launch_bounds__(256, 4) void k_fused(const float* __restrict__ cv,
                                                  const float* __restrict__ wh,
                                                  const int* __restrict__ mask,
                                                  float* __restrict__ sc,
                                                  float* __restrict__ ml,
                                                  float* __restrict__ opart) {
  __shared__ float scpart[256 * 4];   // per-thread score partial float4
  __shared__ float ps[TS];            // exp(score - m_new)
  __shared__ float fbox;              // per-tile rescale factor
  __shared__ float opred[TPB][256];   // final o reduction scratch (8KB)

  const int b = blockIdx.y;
  const int blk = blockIdx.x;
  const int t = threadIdx.x;
  const int rg = t >> 3;              // row-group base (0..31)
  const int cq = t & 7;               // column-quad (0..7)
  const int s_base = blk * (TS * TPB);
  const float* cvb = cv + (size_t)b * D_ * S_;

  // wh values for this thread's 8 rows (rows are the same for every tile)
  float wh8[8];
#pragma unroll
  for (int it = 0; it < 8; ++it) wh8[it] = wh[b * D_ + rg + 32 * it];

  // mask bits for all 8 tiles (used by lanes t<32)
  int mbits[TPB];
  if (t < TS) {
#pragma unroll
    for (int it = 0; it < TPB; ++it)
      mbits[it] = mask[b * S_ + s_base + it * TS + t];
  }

  float o[8];
#pragma unroll
  for (int it = 0; it < 8; ++it) o[it] = 0.f;
  float mrun = -1e30f, lrun = 0.f;    // maintained identically by lanes t<32

  for (int tt = 0; tt < TPB; ++tt) {
    const int s0 = s_base + tt * TS;
    // load this thread's 8x4 register sub-tile (8 x 16B, 128B-chunk coalesced)
    float4 v[8];
#pragma unroll
    for (int it = 0; it < 8; ++it)
      v[it] = *reinterpret_cast<const float4*>(cvb + (size_t)(rg + 32 * it) * S_ + s0 + 4 * cq);

    // score partials for this thread's 4 columns
    float4 p; p.x = 0.f; p.y = 0.f; p.z = 0.f; p.w = 0.f;
#pragma unroll
    for (int it = 0; it < 8; ++it) {
      p.x = fmaf(v[it].x, wh8[it], p.x);
      p.y = fmaf(v[it].y, wh8[it], p.y);
      p.z = fmaf(v[it].z, wh8[it], p.z);
      p.w = fmaf(v[it].w, wh8[it], p.w);
    }
    *reinterpret_cast<float4*>(&scpart[t * 4]) = p;
    __syncthreads();                          // B1: scpart ready

    if (t < TS) {
      // gather column t: contributors are threads 8k + (t>>2), element t&3
      float sv = 0.f;
#pragma unroll
      for (int k = 0; k < 32; ++k)
        sv += scpart[(k * 8 + (t >> 2)) * 4 + (t & 3)];   // bank = t: conflict-free
      if (mbits[tt] != 0) sv = -INFINITY;
      sc[(size_t)b * S_ + s0 + t] = sv;

      float pm = sv;
#pragma unroll
      for (int off = 16; off > 0; off >>= 1) pm = fmaxf(pm, __shfl_xor(pm, off, 64));
      const float mnew = fmaxf(fmaxf(mrun, pm), -1e30f);
      const float f = __expf(mrun - mnew);
      const float e = __expf(sv - mnew);      // masked: exp(-inf)=0
      float pl = e;
#pragma unroll
      for (int off = 16; off > 0; off >>= 1) pl += __shfl_xor(pl, off, 64);
      lrun = lrun * f + pl;
      mrun = mnew;
      ps[t] = e;
      if (t == 0) fbox = f;
    }
    __syncthreads();                          // B2: ps/fbox ready

    const float f = fbox;
    const float4 p4 = *reinterpret_cast<const float4*>(&ps[4 * cq]); // broadcast b128
#pragma unroll
    for (int it = 0; it < 8; ++it) {
      const float add = v[it].x * p4.x + v[it].y * p4.y + v[it].z * p4.z + v[it].w * p4.w;
      o[it] = fmaf(o[it], f, add);
    }
  }

  // reduce o over the 8 column-quad threads per row: opred[it][t]
#pragma unroll
  for (int it = 0; it < 8; ++it) opred[it][t] = o[it];
  __syncthreads();
  // thread t owns output row d = t: contributors t' = 8*(d&31)+c8, it = d>>5
  float od = 0.f;
  const int k0 = 8 * (t & 31);
  const int itq = t >> 5;
#pragma unroll
  for (int c8 = 0; c8 < 8; ++c8) od += opred[itq][k0 + c8];
  opart[((size_t)b * BPB + blk) * D_ + t] = od;
  if (t == 0) {
    ml[((size_t)b * BPB + blk) * 2] = mrun;
    ml[((size_t)b * BPB + blk) * 2 + 1] = lrun;
  }
}

// K3: global stats + ctx reduction. grid (4, B_), 256 threads.
__global__ __launch_bounds__(256) void k_combine(const float* __restrict__ ml,
                                                 const float* __restrict__ opart,
                                                 float* __restrict__ ctx,
                                                 float* __restrict__ mstat) {
  const int xc = blockIdx.x;
  const int b = blockIdx.y;
  const int t = threadIdx.x;
  __shared__ float mls[BPB * 2];
  __shared__ float em[BPB];
  __shared__ float red[4][64];
  if (t < BPB * 2) mls[t] = ml[(size_t)b * BPB * 2 + t];
  __syncthreads();
  float M = -1e30f;
#pragma unroll
  for (int i = 0; i < BPB; ++i) M = fmaxf(M, mls[2 * i]);
  float L = 0.f;
#pragma unroll
  for (int i = 0; i < BPB; ++i) L += mls[2 * i + 1] * __expf(mls[2 * i] - M);
  const float invL = 1.0f / L;
  if (t < BPB) em[t] = __expf(mls[2 * t] - M);
  __syncthreads();

  const int d = xc * 64 + (t & 63);
  const int tq = t >> 6;
  float acc = 0.f;
#pragma unroll
  for (int i = 0; i < 8; ++i) {
    const int ti = tq * 8 + i;
    acc = fmaf(opart[((size_t)b * BPB + ti) * D_ + d], em[ti], acc);
  }
  red[tq][t & 63] = acc;
  __syncthreads();
  if (t < 64) {
    const float r = red[0][t] + red[1][t] + red[2][t] + red[3][t];
    ctx[b * D_ + xc * 64 + t] = r * invL;
  }
  if (xc == 0 && t == 0) { mstat[2 * b] = M; mstat[2 * b + 1] = invL; }
}

// K4: out[0:seqlen,B,D] = ctx broadcast; out[..., seqlen,B,S] = exp(sc-M)*invL
__global__ __launch_bounds__(256) void k_bcast(const float4* __restrict__ ctx4,
                                               const float* __restrict__ sc,
                                               const float* __restrict__ mstat,
                                               float4* __restrict__ out4,
                                               long ctxQuads, long total4) {
  const long stride = (long)gridDim.x * blockDim.x;
  for (long idx = (long)blockIdx.x * blockDim.x + threadIdx.x; idx < total4;
       idx += stride) {
    if (idx < ctxQuads) {
      out4[idx] = ctx4[idx & (long)(B_ * D_ / 4 - 1)];
    } else {
      const long q = idx - ctxQuads;
      const long qq = q & (long)(B_ * S_ / 4 - 1);
      const int b = (int)(qq >> 11);                 // / (S_/4)
      const int sq = (int)(qq & (S_ / 4 - 1));
      const float M = mstat[b * 2], invL = mstat[b * 2 + 1];
      const float4 v = *reinterpret_cast<const float4*>(sc + (size_t)b * S_ + 4 * sq);
      float4 r;
      r.x = __expf(v.x - M) * invL;
      r.y = __expf(v.y - M) * invL;
      r.z = __expf(v.z - M) * invL;
      r.w = __expf(v.w - M) * invL;
      out4[idx] = r;
    }
  }
}

extern "C" void kernel_launch(void* const* d_in, const int* in_sizes, int n_in,
                              void* d_out, int out_size, void* d_ws, size_t ws_size,
                              hipStream_t stream) {
  // inputs: 0=seqlen(1), 1=hidden(B*D), 2=contextvects(B*D*S), 3=W(D*D),
  //         4=b(D) [softmax-invariant, dropped], 5=padding_mask(B*S)
  const float* hidden = (const float*)d_in[1];
  const float* cv = (const float*)d_in[2];
  const float* W = (const float*)d_in[3];
  const int* mask = (const int*)d_in[5];

  float* ws = (float*)d_ws;
  float* wh = ws;
  float* ctx = ws + 8192;
  float* sc = ws + 16384;
  float* ml = ws + 278528;
  float* opart = ws + 280576;
  float* mstat = ws + 542720;

  k_wh<<<B_, D_, 0, stream>>>(W, hidden, wh);
  k_fused<<<dim3(BPB, B_), 256, 0, stream>>>(cv, wh, mask, sc, ml, opart);
  k_combine<<<dim3(4, B_), 256, 0, stream>>>(ml, opart, ctx, mstat);

  const long seqlen = (long)out_size / (B_ * D_ + B_ * S_);
  const long ctxQuads = seqlen * B_ * D_ / 4;
  const long total4 = (long)out_size / 4;
  k_bcast<<<2048, 256, 0, stream>>>((const float4*)ctx, sc, mstat,
                                    (float4*)d_out, ctxQuads, total4);
}